// Round 2
// baseline (6483.873 us; speedup 1.0000x reference)
//
#include <hip/hip_runtime.h>
#include <hip/hip_bf16.h>

// Model dims (fixed)
#define DIMM 128
#define TT   40
#define BB   4096
#define NTOK (BB*TT)           // 163840
#define NLAY 3

typedef float f4 __attribute__((ext_vector_type(4)));

__device__ __forceinline__ float bf2f(unsigned short u) {
    union { unsigned int i; float f; } v; v.i = ((unsigned int)u) << 16; return v.f;
}

// ---------------- pack QKV weights into one [128][384] per layer ----------------
__global__ __launch_bounds__(256) void pack_qkv_k(
    const float* __restrict__ qt, const float* __restrict__ kt,
    const float* __restrict__ qs, const float* __restrict__ ks,
    const float* __restrict__ vw, float* __restrict__ Wq)
{
    int idx = blockIdx.x * 256 + threadIdx.x;      // 3*128*384 = 147456 exactly
    int i = idx / 49152;
    int rem = idx % 49152;
    int r = rem / 384, c = rem % 384;
    float v;
    if (c < 32)        v = qt[i*4096  + r*32  + c];
    else if (c < 64)   v = kt[i*4096  + r*32  + (c-32)];
    else if (c < 160)  v = qs[i*12288 + r*96  + (c-64)];
    else if (c < 256)  v = ks[i*12288 + r*96  + (c-160)];
    else               v = vw[i*16384 + r*128 + (c-256)];
    Wq[idx] = v;
}

// ---------------- embedding: h = x @ embed_w + embed_b + pos ----------------
__global__ __launch_bounds__(256) void embed_k(
    const float* __restrict__ x, const float* __restrict__ ew,
    const float* __restrict__ eb, const float* __restrict__ pos,
    float* __restrict__ h)
{
    int idx = blockIdx.x * 256 + threadIdx.x;      // NTOK*128
    int n = idx >> 7, d = idx & 127;
    int t = n % TT;
    const float* xr = x + (size_t)n * 6;
    float acc = eb[d] + pos[t*128 + d];
    #pragma unroll
    for (int k = 0; k < 6; ++k) acc += xr[k] * ew[k*128 + d];
    h[idx] = acc;
}

// ---------------- mln stats: per token mean, rstd, mq; block partial of |mq| ----------------
__global__ __launch_bounds__(256) void mln_stats_k(
    const float* __restrict__ h, const float* __restrict__ pg, const float* __restrict__ pb,
    float* __restrict__ stats, float* __restrict__ partials)
{
    int wid = threadIdx.x >> 6, lane = threadIdx.x & 63;
    int tok = blockIdx.x * 4 + wid;
    const float* hr = h + (size_t)tok * 128;
    float x0 = hr[lane], x1 = hr[lane + 64];
    float s = x0 + x1;
    #pragma unroll
    for (int o = 32; o > 0; o >>= 1) s += __shfl_xor(s, o);
    float m = s * (1.f / 128.f);
    float d0 = x0 - m, d1 = x1 - m;
    float v = d0*d0 + d1*d1;
    #pragma unroll
    for (int o = 32; o > 0; o >>= 1) v += __shfl_xor(v, o);
    float rstd = rsqrtf(v * (1.f / 128.f) + 1e-5f);
    float y0 = d0 * rstd * pg[lane]      + pb[lane];
    float y1 = d1 * rstd * pg[lane + 64] + pb[lane + 64];
    // dims 0..31 are "t" (negative), 32..127 are "s" (positive)
    float q = (lane < 32 ? -(y0*y0) : (y0*y0)) + y1*y1;
    #pragma unroll
    for (int o = 32; o > 0; o >>= 1) q += __shfl_xor(q, o);
    if (lane == 0) {
        stats[(size_t)tok*4 + 0] = m;
        stats[(size_t)tok*4 + 1] = rstd;
        stats[(size_t)tok*4 + 2] = q;
    }
    __shared__ float pm[4];
    if (lane == 0) pm[wid] = fabsf(q);
    __syncthreads();
    if (threadIdx.x == 0) partials[blockIdx.x] = (pm[0] + pm[1]) + (pm[2] + pm[3]);
}

// ---------------- reduce partials -> eps scalar (deterministic) ----------------
__global__ __launch_bounds__(256) void reduce_eps_k(
    const float* __restrict__ partials, int n, float* __restrict__ scal)
{
    float s = 0.f;
    for (int i = threadIdx.x; i < n; i += 256) s += partials[i];
    __shared__ float sm[256];
    sm[threadIdx.x] = s;
    __syncthreads();
    for (int o = 128; o > 0; o >>= 1) {
        if (threadIdx.x < o) sm[threadIdx.x] += sm[threadIdx.x + o];
        __syncthreads();
    }
    if (threadIdx.x == 0) {
        float mean = sm[0] / (float)NTOK;
        scal[0] = fmaxf(0.01f * mean, 1e-5f);
    }
}

// ---------------- finalize per-token scale = 1/(sqrt(|mq|+eps)+eps) ----------------
__global__ __launch_bounds__(256) void finalize_k(float* __restrict__ stats, const float* __restrict__ scal)
{
    int tok = blockIdx.x * 256 + threadIdx.x;      // 640*256 = NTOK
    float eps = scal[0];
    float mq = stats[(size_t)tok*4 + 2];
    stats[(size_t)tok*4 + 3] = 1.f / (sqrtf(fabsf(mq) + eps) + eps);
}

// ---------------- generic tiled GEMM ----------------
// C[M x Nc] = A[M x K] @ W[K x Nc]
// AMODE 0: A = mln-transform of h (K must be 128)
// AMODE 1: A = bf16 buffer (ld 512), columns acol0 + k
// EPI 0: store bf16 to obuf (+bias)      EPI 1: gelu(bias+C) -> bf16 obuf
// EPI 2: hres += C + bias (f32 residual)
template<int AMODE, int EPI>
__global__ __launch_bounds__(256) void gemm_k(
    const float* __restrict__ hbuf, const float* __restrict__ stats,
    const float* __restrict__ pg, const float* __restrict__ pb,
    const float* __restrict__ gg, const float* __restrict__ gb,
    const unsigned short* __restrict__ abuf, int acol0,
    const float* __restrict__ W, int ldw,
    const float* __restrict__ bias,
    __hip_bfloat16* __restrict__ obuf, int ocol0,
    float* __restrict__ hres, int K)
{
    __shared__ float As[64][132];
    __shared__ float Ws[64][132];   // transposed: Ws[col][k]
    const int tid = threadIdx.x;
    const int tx = tid & 15, ty = tid >> 4;
    const int row0 = blockIdx.y * 64, col0 = blockIdx.x * 64;
    float acc[4][4] = {};

    for (int kk = 0; kk < K; kk += 128) {
        __syncthreads();
        // ---- stage A tile: 64 rows x 128 cols ----
        {
            int r = tid >> 5, c4 = (tid & 31) * 4;
            #pragma unroll
            for (int p = 0; p < 8; ++p, r += 8) {
                int tok = row0 + r;
                f4 y;
                if (AMODE == 0) {
                    f4 x = *(const f4*)(hbuf + (size_t)tok*128 + c4);
                    float m  = stats[(size_t)tok*4 + 0];
                    float rs = stats[(size_t)tok*4 + 1];
                    float s3 = stats[(size_t)tok*4 + 3];
                    #pragma unroll
                    for (int j = 0; j < 4; ++j) {
                        int c = c4 + j;
                        y[j] = gg[c] * (((x[j] - m) * rs * pg[c] + pb[c]) * s3) + gb[c];
                    }
                } else {
                    const unsigned short* src = abuf + (size_t)tok*512 + acol0 + kk + c4;
                    ushort4 u = *(const ushort4*)src;
                    y[0] = bf2f(u.x); y[1] = bf2f(u.y); y[2] = bf2f(u.z); y[3] = bf2f(u.w);
                }
                *(f4*)(&As[r][c4]) = y;
            }
        }
        // ---- stage W tile transposed: Ws[c][kloc] ----
        {
            int c = tid & 63, kr = tid >> 6;
            #pragma unroll
            for (int p = 0; p < 32; ++p, kr += 4) {
                Ws[c][kr] = W[(size_t)(kk + kr) * ldw + col0 + c];
            }
        }
        __syncthreads();
        // ---- compute ----
        for (int k = 0; k < 128; k += 4) {
            f4 a[4], w[4];
            #pragma unroll
            for (int i = 0; i < 4; ++i) a[i] = *(const f4*)(&As[ty + 16*i][k]);
            #pragma unroll
            for (int j = 0; j < 4; ++j) w[j] = *(const f4*)(&Ws[tx + 16*j][k]);
            #pragma unroll
            for (int i = 0; i < 4; ++i)
                #pragma unroll
                for (int j = 0; j < 4; ++j)
                    acc[i][j] += a[i][0]*w[j][0] + a[i][1]*w[j][1]
                               + a[i][2]*w[j][2] + a[i][3]*w[j][3];
        }
    }
    // ---- epilogue ----
    #pragma unroll
    for (int i = 0; i < 4; ++i) {
        int row = row0 + ty + 16*i;
        #pragma unroll
        for (int j = 0; j < 4; ++j) {
            int col = tx + 16*j;
            float v = acc[i][j];
            if (bias) v += bias[col0 + col];
            if (EPI == 1) v = 0.5f * v * (1.f + erff(v * 0.70710678118654752f));
            if (EPI <= 1) obuf[(size_t)row*512 + ocol0 + col0 + col] = __float2bfloat16(v);
            else          hres[(size_t)row*128 + col0 + col] += v;
        }
    }
}

// ---------------- attention: block per batch, wave per head ----------------
__global__ __launch_bounds__(256) void attn_k(__hip_bfloat16* __restrict__ buf,
                                              const float* __restrict__ wsp)
{
    __shared__ float Q[4][40][33], K[4][40][33], V[4][40][33];
    int b = blockIdx.x;
    int h = threadIdx.x >> 6, lane = threadIdx.x & 63;
    int qcol = (h == 0) ? 0  : 64  + (h-1)*32;
    int kcol = (h == 0) ? 32 : 160 + (h-1)*32;
    int vcol = 256 + h*32;
    const unsigned short* bb = (const unsigned short*)buf;
    for (int e = lane; e < 1280; e += 64) {
        int t = e >> 5, d = e & 31;
        size_t ro = (size_t)(b*TT + t) * 512;
        Q[h][t][d] = bf2f(bb[ro + qcol + d]);
        K[h][t][d] = bf2f(bb[ro + kcol + d]);
        V[h][t][d] = bf2f(bb[ro + vcol + d]);
    }
    __syncthreads();
    const float scale = 0.17677669529663687f;   // 32^-0.5
    float wmul = scale;
    if (h == 0) { float w = wsp[0]; wmul = -scale / (1.f + expf(-w)); }
    for (int t = 0; t < 40; ++t) {
        float sc = -1e30f;
        if (lane < 40) {
            float dot = 0.f;
            #pragma unroll
            for (int k = 0; k < 32; ++k) dot += Q[h][t][k] * K[h][lane][k];
            sc = wmul * dot;
        }
        float mx = sc;
        #pragma unroll
        for (int o = 32; o > 0; o >>= 1) mx = fmaxf(mx, __shfl_xor(mx, o));
        float p = (lane < 40) ? expf(sc - mx) : 0.f;
        float sum = p;
        #pragma unroll
        for (int o = 32; o > 0; o >>= 1) sum += __shfl_xor(sum, o);
        float a = p / sum;
        float acc = 0.f;
        for (int s = 0; s < 40; ++s) {
            float as = __shfl(a, s);
            acc += as * V[h][s][lane & 31];
        }
        if (lane < 32) {
            size_t ro = (size_t)(b*TT + t) * 512;
            buf[ro + 384 + h*32 + lane] = __float2bfloat16(acc);
        }
    }
}

// ---------------- head: last token -> mln -> @traj_w + traj_b (f32 output!) ----------------
__global__ __launch_bounds__(128) void head_k(
    const float* __restrict__ h, const float* __restrict__ stats,
    const float* __restrict__ pg, const float* __restrict__ pb,
    const float* __restrict__ gg, const float* __restrict__ gb,
    const float* __restrict__ tw, const float* __restrict__ tb,
    float* __restrict__ out)
{
    int b = blockIdx.x, tid = threadIdx.x;
    int tok = b*TT + (TT - 1);
    __shared__ float y[128];
    float m  = stats[(size_t)tok*4 + 0];
    float rs = stats[(size_t)tok*4 + 1];
    float s3 = stats[(size_t)tok*4 + 3];
    float x = h[(size_t)tok*128 + tid];
    y[tid] = gg[tid] * (((x - m) * rs * pg[tid] + pb[tid]) * s3) + gb[tid];
    __syncthreads();
    if (tid < 120) {
        float acc = tb[tid];
        #pragma unroll 4
        for (int d = 0; d < 128; ++d) acc += y[d] * tw[d*120 + tid];
        out[(size_t)b*120 + tid] = acc;   // float32 output, matches reference dtype
    }
}

extern "C" void kernel_launch(void* const* d_in, const int* in_sizes, int n_in,
                              void* d_out, int out_size, void* d_ws, size_t ws_size,
                              hipStream_t stream) {
    const float* x        = (const float*)d_in[0];
    const float* embed_w  = (const float*)d_in[1];
    const float* embed_b  = (const float*)d_in[2];
    const float* pos      = (const float*)d_in[3];
    const float* qt_w     = (const float*)d_in[4];
    const float* kt_w     = (const float*)d_in[5];
    const float* qs_w     = (const float*)d_in[6];
    const float* ks_w     = (const float*)d_in[7];
    const float* v_w      = (const float*)d_in[8];
    const float* out_w    = (const float*)d_in[9];
    const float* out_b    = (const float*)d_in[10];
    const float* w_sigma  = (const float*)d_in[11];
    const float* n1_pre_g = (const float*)d_in[12];
    const float* n1_pre_b = (const float*)d_in[13];
    const float* n1_g     = (const float*)d_in[14];
    const float* n1_b     = (const float*)d_in[15];
    const float* n2_pre_g = (const float*)d_in[16];
    const float* n2_pre_b = (const float*)d_in[17];
    const float* n2_g     = (const float*)d_in[18];
    const float* n2_b     = (const float*)d_in[19];
    const float* ff_w1    = (const float*)d_in[20];
    const float* ff_b1    = (const float*)d_in[21];
    const float* ff_w2    = (const float*)d_in[22];
    const float* ff_b2    = (const float*)d_in[23];
    const float* fn_pre_g = (const float*)d_in[24];
    const float* fn_pre_b = (const float*)d_in[25];
    const float* fn_g     = (const float*)d_in[26];
    const float* fn_b     = (const float*)d_in[27];
    const float* traj_w   = (const float*)d_in[28];
    const float* traj_b   = (const float*)d_in[29];

    char* ws = (char*)d_ws;
    float*          h        = (float*)ws;                          // 83,886,080 B
    float*          stats    = (float*)(ws + 83886080);             //  2,621,440 B
    __hip_bfloat16* buf      = (__hip_bfloat16*)(ws + 86507520);    // 167,772,160 B  (NTOK x 512 bf16)
    float*          Wq       = (float*)(ws + 254279680);            //    589,824 B
    float*          partials = (float*)(ws + 254869504);            //    163,840 B
    float*          scal     = (float*)(ws + 255033344);            //        256 B
    const unsigned short* bufu = (const unsigned short*)buf;

    pack_qkv_k<<<576, 256, 0, stream>>>(qt_w, kt_w, qs_w, ks_w, v_w, Wq);
    embed_k<<<81920, 256, 0, stream>>>(x, embed_w, embed_b, pos, h);

    for (int i = 0; i < NLAY; ++i) {
        // ---- mln1 + attention block ----
        mln_stats_k<<<40960, 256, 0, stream>>>(h, n1_pre_g + i*128, n1_pre_b + i*128, stats, partials);
        reduce_eps_k<<<1, 256, 0, stream>>>(partials, 40960, scal);
        finalize_k<<<640, 256, 0, stream>>>(stats, scal);
        gemm_k<0,0><<<dim3(6,2560), 256, 0, stream>>>(
            h, stats, n1_pre_g + i*128, n1_pre_b + i*128, n1_g + i*128, n1_b + i*128,
            nullptr, 0, Wq + (size_t)i*49152, 384, nullptr, buf, 0, nullptr, 128);
        attn_k<<<4096, 256, 0, stream>>>(buf, w_sigma + i);
        gemm_k<1,2><<<dim3(2,2560), 256, 0, stream>>>(
            nullptr, nullptr, nullptr, nullptr, nullptr, nullptr,
            bufu, 384, out_w + (size_t)i*16384, 128, out_b + i*128, nullptr, 0, h, 128);
        // ---- mln2 + FFN block ----
        mln_stats_k<<<40960, 256, 0, stream>>>(h, n2_pre_g + i*128, n2_pre_b + i*128, stats, partials);
        reduce_eps_k<<<1, 256, 0, stream>>>(partials, 40960, scal);
        finalize_k<<<640, 256, 0, stream>>>(stats, scal);
        gemm_k<0,1><<<dim3(8,2560), 256, 0, stream>>>(
            h, stats, n2_pre_g + i*128, n2_pre_b + i*128, n2_g + i*128, n2_b + i*128,
            nullptr, 0, ff_w1 + (size_t)i*65536, 512, ff_b1 + i*512, buf, 0, nullptr, 128);
        gemm_k<1,2><<<dim3(2,2560), 256, 0, stream>>>(
            nullptr, nullptr, nullptr, nullptr, nullptr, nullptr,
            bufu, 0, ff_w2 + (size_t)i*65536, 128, ff_b2 + i*128, nullptr, 0, h, 512);
    }

    // ---- final mln + head ----
    mln_stats_k<<<40960, 256, 0, stream>>>(h, fn_pre_g, fn_pre_b, stats, partials);
    reduce_eps_k<<<1, 256, 0, stream>>>(partials, 40960, scal);
    finalize_k<<<640, 256, 0, stream>>>(stats, scal);
    head_k<<<4096, 128, 0, stream>>>(h, stats, fn_pre_g, fn_pre_b, fn_g, fn_b,
                                     traj_w, traj_b, (float*)d_out);
}

// Round 3
// 4898.356 us; speedup vs baseline: 1.3237x; 1.3237x over previous
//
#include <hip/hip_runtime.h>
#include <hip/hip_bf16.h>

// Model dims (fixed)
#define DIMM 128
#define TT   40
#define BB   4096
#define NTOK (BB*TT)           // 163840
#define NLAY 3

typedef float f4 __attribute__((ext_vector_type(4)));

__device__ __forceinline__ float bf2f(unsigned short u) {
    union { unsigned int i; float f; } v; v.i = ((unsigned int)u) << 16; return v.f;
}
__device__ __forceinline__ unsigned short f2bu(float f) {
    __hip_bfloat16 h = __float2bfloat16(f);
    return *reinterpret_cast<unsigned short*>(&h);
}

// ---------------- pack QKV weights into one [128][384] per layer ----------------
__global__ __launch_bounds__(256) void pack_qkv_k(
    const float* __restrict__ qt, const float* __restrict__ kt,
    const float* __restrict__ qs, const float* __restrict__ ks,
    const float* __restrict__ vw, float* __restrict__ Wq)
{
    int idx = blockIdx.x * 256 + threadIdx.x;      // 3*128*384 = 147456 exactly
    int i = idx / 49152;
    int rem = idx % 49152;
    int r = rem / 384, c = rem % 384;
    float v;
    if (c < 32)        v = qt[i*4096  + r*32  + c];
    else if (c < 64)   v = kt[i*4096  + r*32  + (c-32)];
    else if (c < 160)  v = qs[i*12288 + r*96  + (c-64)];
    else if (c < 256)  v = ks[i*12288 + r*96  + (c-160)];
    else               v = vw[i*16384 + r*128 + (c-256)];
    Wq[idx] = v;
}

// ---------------- embedding: h = x @ embed_w + embed_b + pos ----------------
__global__ __launch_bounds__(256) void embed_k(
    const float* __restrict__ x, const float* __restrict__ ew,
    const float* __restrict__ eb, const float* __restrict__ pos,
    float* __restrict__ h)
{
    int idx = blockIdx.x * 256 + threadIdx.x;      // NTOK*128
    int n = idx >> 7, d = idx & 127;
    int t = n % TT;
    const float* xr = x + (size_t)n * 6;
    float acc = eb[d] + pos[t*128 + d];
    #pragma unroll
    for (int k = 0; k < 6; ++k) acc += xr[k] * ew[k*128 + d];
    h[idx] = acc;
}

// ---------------- mln stats: per token mean, rstd, mq; block partial of |mq| ----------------
__global__ __launch_bounds__(256) void mln_stats_k(
    const float* __restrict__ h, const float* __restrict__ pg, const float* __restrict__ pb,
    float* __restrict__ stats, float* __restrict__ partials)
{
    int wid = threadIdx.x >> 6, lane = threadIdx.x & 63;
    int tok = blockIdx.x * 4 + wid;
    const float* hr = h + (size_t)tok * 128;
    float x0 = hr[lane], x1 = hr[lane + 64];
    float s = x0 + x1;
    #pragma unroll
    for (int o = 32; o > 0; o >>= 1) s += __shfl_xor(s, o);
    float m = s * (1.f / 128.f);
    float d0 = x0 - m, d1 = x1 - m;
    float v = d0*d0 + d1*d1;
    #pragma unroll
    for (int o = 32; o > 0; o >>= 1) v += __shfl_xor(v, o);
    float rstd = rsqrtf(v * (1.f / 128.f) + 1e-5f);
    float y0 = d0 * rstd * pg[lane]      + pb[lane];
    float y1 = d1 * rstd * pg[lane + 64] + pb[lane + 64];
    // dims 0..31 are "t" (negative), 32..127 are "s" (positive)
    float q = (lane < 32 ? -(y0*y0) : (y0*y0)) + y1*y1;
    #pragma unroll
    for (int o = 32; o > 0; o >>= 1) q += __shfl_xor(q, o);
    if (lane == 0) {
        stats[(size_t)tok*4 + 0] = m;
        stats[(size_t)tok*4 + 1] = rstd;
        stats[(size_t)tok*4 + 2] = q;
    }
    __shared__ float pm[4];
    if (lane == 0) pm[wid] = fabsf(q);
    __syncthreads();
    if (threadIdx.x == 0) partials[blockIdx.x] = (pm[0] + pm[1]) + (pm[2] + pm[3]);
}

// ---------------- reduce partials -> eps scalar (deterministic) ----------------
__global__ __launch_bounds__(256) void reduce_eps_k(
    const float* __restrict__ partials, int n, float* __restrict__ scal)
{
    float s = 0.f;
    for (int i = threadIdx.x; i < n; i += 256) s += partials[i];
    __shared__ float sm[256];
    sm[threadIdx.x] = s;
    __syncthreads();
    for (int o = 128; o > 0; o >>= 1) {
        if (threadIdx.x < o) sm[threadIdx.x] += sm[threadIdx.x + o];
        __syncthreads();
    }
    if (threadIdx.x == 0) {
        float mean = sm[0] / (float)NTOK;
        scal[0] = fmaxf(0.01f * mean, 1e-5f);
    }
}

// ---------------- finalize per-token scale = 1/(sqrt(|mq|+eps)+eps) ----------------
__global__ __launch_bounds__(256) void finalize_k(float* __restrict__ stats, const float* __restrict__ scal)
{
    int tok = blockIdx.x * 256 + threadIdx.x;      // 640*256 = NTOK
    float eps = scal[0];
    float mq = stats[(size_t)tok*4 + 2];
    stats[(size_t)tok*4 + 3] = 1.f / (sqrtf(fabsf(mq) + eps) + eps);
}

// ---------------- generic tiled GEMM ----------------
// C[M x Nc] = A[M x K] @ W[K x Nc]
// AMODE 0: A = mln-transform of h (K must be 128)
// AMODE 1: A = bf16 buffer (ld 512), columns acol0 + k
// EPI 0: store bf16 to obuf (+bias)      EPI 1: gelu(bias+C) -> bf16 obuf
// EPI 2: hres += C + bias (f32 residual)
template<int AMODE, int EPI>
__global__ __launch_bounds__(256) void gemm_k(
    const float* __restrict__ hbuf, const float* __restrict__ stats,
    const float* __restrict__ pg, const float* __restrict__ pb,
    const float* __restrict__ gg, const float* __restrict__ gb,
    const unsigned short* __restrict__ abuf, int acol0,
    const float* __restrict__ W, int ldw,
    const float* __restrict__ bias,
    __hip_bfloat16* __restrict__ obuf, int ocol0,
    float* __restrict__ hres, int K)
{
    __shared__ float As[64][132];
    __shared__ float Ws[64][132];   // transposed: Ws[col][k]
    const int tid = threadIdx.x;
    const int tx = tid & 15, ty = tid >> 4;
    const int row0 = blockIdx.y * 64, col0 = blockIdx.x * 64;
    float acc[4][4] = {};

    for (int kk = 0; kk < K; kk += 128) {
        __syncthreads();
        // ---- stage A tile: 64 rows x 128 cols ----
        {
            int r = tid >> 5, c4 = (tid & 31) * 4;
            #pragma unroll
            for (int p = 0; p < 8; ++p, r += 8) {
                int tok = row0 + r;
                f4 y;
                if (AMODE == 0) {
                    f4 x = *(const f4*)(hbuf + (size_t)tok*128 + c4);
                    float m  = stats[(size_t)tok*4 + 0];
                    float rs = stats[(size_t)tok*4 + 1];
                    float s3 = stats[(size_t)tok*4 + 3];
                    #pragma unroll
                    for (int j = 0; j < 4; ++j) {
                        int c = c4 + j;
                        y[j] = gg[c] * (((x[j] - m) * rs * pg[c] + pb[c]) * s3) + gb[c];
                    }
                } else {
                    const unsigned short* src = abuf + (size_t)tok*512 + acol0 + kk + c4;
                    ushort4 u = *(const ushort4*)src;
                    y[0] = bf2f(u.x); y[1] = bf2f(u.y); y[2] = bf2f(u.z); y[3] = bf2f(u.w);
                }
                *(f4*)(&As[r][c4]) = y;
            }
        }
        // ---- stage W tile transposed: Ws[c][kloc] ----
        {
            int c = tid & 63, kr = tid >> 6;
            #pragma unroll
            for (int p = 0; p < 32; ++p, kr += 4) {
                Ws[c][kr] = W[(size_t)(kk + kr) * ldw + col0 + c];
            }
        }
        __syncthreads();
        // ---- compute ----
        for (int k = 0; k < 128; k += 4) {
            f4 a[4], w[4];
            #pragma unroll
            for (int i = 0; i < 4; ++i) a[i] = *(const f4*)(&As[ty + 16*i][k]);
            #pragma unroll
            for (int j = 0; j < 4; ++j) w[j] = *(const f4*)(&Ws[tx + 16*j][k]);
            #pragma unroll
            for (int i = 0; i < 4; ++i)
                #pragma unroll
                for (int j = 0; j < 4; ++j)
                    acc[i][j] += a[i][0]*w[j][0] + a[i][1]*w[j][1]
                               + a[i][2]*w[j][2] + a[i][3]*w[j][3];
        }
    }
    // ---- epilogue ----
    #pragma unroll
    for (int i = 0; i < 4; ++i) {
        int row = row0 + ty + 16*i;
        #pragma unroll
        for (int j = 0; j < 4; ++j) {
            int col = tx + 16*j;
            float v = acc[i][j];
            if (bias) v += bias[col0 + col];
            if (EPI == 1) v = 0.5f * v * (1.f + erff(v * 0.70710678118654752f));
            if (EPI <= 1) obuf[(size_t)row*512 + ocol0 + col0 + col] = __float2bfloat16(v);
            else          hres[(size_t)row*128 + col0 + col] += v;
        }
    }
}

// ---------------- attention: block per batch, THREAD per (head, query) ----------------
// K/V staged f32 in LDS (40 KB exactly); scores/accumulator fully in registers.
__global__ __launch_bounds__(256) void attn_k(__hip_bfloat16* __restrict__ buf,
                                              const float* __restrict__ wsp)
{
    __shared__ float Kl[4][40][32];
    __shared__ float Vl[4][40][32];
    int b = blockIdx.x;
    int tid = threadIdx.x;
    const unsigned short* bb = (const unsigned short*)buf;

    // cooperative stage: 1280 quads of K + V (bf16 -> f32)
    for (int e = tid; e < 1280; e += 256) {
        int r = e >> 3, q4 = (e & 7) << 2;     // r in [0,160): h*40+t ; q4: dim quad
        int h = r / 40, t = r - h * 40;
        const unsigned short* src = bb + (size_t)(b*TT + t) * 512;
        int kcol = (h == 0) ? 32 : 128 + h*32;
        ushort4 uk = *(const ushort4*)(src + kcol + q4);
        ushort4 uv = *(const ushort4*)(src + 256 + h*32 + q4);
        f4 fk, fv;
        fk[0]=bf2f(uk.x); fk[1]=bf2f(uk.y); fk[2]=bf2f(uk.z); fk[3]=bf2f(uk.w);
        fv[0]=bf2f(uv.x); fv[1]=bf2f(uv.y); fv[2]=bf2f(uv.z); fv[3]=bf2f(uv.w);
        *(f4*)(&Kl[h][t][q4]) = fk;
        *(f4*)(&Vl[h][t][q4]) = fv;
    }
    __syncthreads();
    if (tid >= 160) return;

    int h = tid / 40, t = tid - h * 40;
    size_t ro = (size_t)(b*TT + t) * 512;
    int qcol = (h == 0) ? 0 : 32 + h*32;

    float q[32];
    #pragma unroll
    for (int k = 0; k < 32; k += 4) {
        ushort4 u = *(const ushort4*)(bb + ro + qcol + k);
        q[k]=bf2f(u.x); q[k+1]=bf2f(u.y); q[k+2]=bf2f(u.z); q[k+3]=bf2f(u.w);
    }
    const float scale = 0.17677669529663687f;   // 32^-0.5
    float wmul = scale;
    if (h == 0) wmul = -scale / (1.f + __expf(-wsp[0]));

    float sc[40];
    float mx = -1e30f;
    #pragma unroll
    for (int s = 0; s < 40; ++s) {
        float dot = 0.f;
        #pragma unroll
        for (int k = 0; k < 32; k += 4) {
            const f4 kv = *(const f4*)(&Kl[h][s][k]);
            dot += q[k]*kv[0] + q[k+1]*kv[1] + q[k+2]*kv[2] + q[k+3]*kv[3];
        }
        float v = wmul * dot;
        sc[s] = v;
        mx = fmaxf(mx, v);
    }
    float sum = 0.f;
    #pragma unroll
    for (int s = 0; s < 40; ++s) { float p = __expf(sc[s] - mx); sc[s] = p; sum += p; }
    float inv = 1.f / sum;

    float acc[32] = {};
    #pragma unroll
    for (int s = 0; s < 40; ++s) {
        float p = sc[s];
        #pragma unroll
        for (int k = 0; k < 32; k += 4) {
            const f4 vv = *(const f4*)(&Vl[h][s][k]);
            acc[k]   += p*vv[0]; acc[k+1] += p*vv[1];
            acc[k+2] += p*vv[2]; acc[k+3] += p*vv[3];
        }
    }
    unsigned short* bw = (unsigned short*)buf;
    #pragma unroll
    for (int k = 0; k < 32; k += 4) {
        ushort4 u;
        u.x = f2bu(acc[k]  *inv); u.y = f2bu(acc[k+1]*inv);
        u.z = f2bu(acc[k+2]*inv); u.w = f2bu(acc[k+3]*inv);
        *(ushort4*)(bw + ro + 384 + h*32 + k) = u;
    }
}

// ---------------- head: last token -> mln -> @traj_w + traj_b (f32 output) ----------------
__global__ __launch_bounds__(128) void head_k(
    const float* __restrict__ h, const float* __restrict__ stats,
    const float* __restrict__ pg, const float* __restrict__ pb,
    const float* __restrict__ gg, const float* __restrict__ gb,
    const float* __restrict__ tw, const float* __restrict__ tb,
    float* __restrict__ out)
{
    int b = blockIdx.x, tid = threadIdx.x;
    int tok = b*TT + (TT - 1);
    __shared__ float y[128];
    float m  = stats[(size_t)tok*4 + 0];
    float rs = stats[(size_t)tok*4 + 1];
    float s3 = stats[(size_t)tok*4 + 3];
    float x = h[(size_t)tok*128 + tid];
    y[tid] = gg[tid] * (((x - m) * rs * pg[tid] + pb[tid]) * s3) + gb[tid];
    __syncthreads();
    if (tid < 120) {
        float acc = tb[tid];
        #pragma unroll 4
        for (int d = 0; d < 128; ++d) acc += y[d] * tw[d*120 + tid];
        out[(size_t)b*120 + tid] = acc;   // float32 output, matches reference dtype
    }
}

extern "C" void kernel_launch(void* const* d_in, const int* in_sizes, int n_in,
                              void* d_out, int out_size, void* d_ws, size_t ws_size,
                              hipStream_t stream) {
    const float* x        = (const float*)d_in[0];
    const float* embed_w  = (const float*)d_in[1];
    const float* embed_b  = (const float*)d_in[2];
    const float* pos      = (const float*)d_in[3];
    const float* qt_w     = (const float*)d_in[4];
    const float* kt_w     = (const float*)d_in[5];
    const float* qs_w     = (const float*)d_in[6];
    const float* ks_w     = (const float*)d_in[7];
    const float* v_w      = (const float*)d_in[8];
    const float* out_w    = (const float*)d_in[9];
    const float* out_b    = (const float*)d_in[10];
    const float* w_sigma  = (const float*)d_in[11];
    const float* n1_pre_g = (const float*)d_in[12];
    const float* n1_pre_b = (const float*)d_in[13];
    const float* n1_g     = (const float*)d_in[14];
    const float* n1_b     = (const float*)d_in[15];
    const float* n2_pre_g = (const float*)d_in[16];
    const float* n2_pre_b = (const float*)d_in[17];
    const float* n2_g     = (const float*)d_in[18];
    const float* n2_b     = (const float*)d_in[19];
    const float* ff_w1    = (const float*)d_in[20];
    const float* ff_b1    = (const float*)d_in[21];
    const float* ff_w2    = (const float*)d_in[22];
    const float* ff_b2    = (const float*)d_in[23];
    const float* fn_pre_g = (const float*)d_in[24];
    const float* fn_pre_b = (const float*)d_in[25];
    const float* fn_g     = (const float*)d_in[26];
    const float* fn_b     = (const float*)d_in[27];
    const float* traj_w   = (const float*)d_in[28];
    const float* traj_b   = (const float*)d_in[29];

    char* ws = (char*)d_ws;
    float*          h        = (float*)ws;                          // 83,886,080 B
    float*          stats    = (float*)(ws + 83886080);             //  2,621,440 B
    __hip_bfloat16* buf      = (__hip_bfloat16*)(ws + 86507520);    // 167,772,160 B  (NTOK x 512 bf16)
    float*          Wq       = (float*)(ws + 254279680);            //    589,824 B
    float*          partials = (float*)(ws + 254869504);            //    163,840 B
    float*          scal     = (float*)(ws + 255033344);            //        256 B
    const unsigned short* bufu = (const unsigned short*)buf;

    pack_qkv_k<<<576, 256, 0, stream>>>(qt_w, kt_w, qs_w, ks_w, v_w, Wq);
    embed_k<<<81920, 256, 0, stream>>>(x, embed_w, embed_b, pos, h);

    for (int i = 0; i < NLAY; ++i) {
        // ---- mln1 + attention block ----
        mln_stats_k<<<40960, 256, 0, stream>>>(h, n1_pre_g + i*128, n1_pre_b + i*128, stats, partials);
        reduce_eps_k<<<1, 256, 0, stream>>>(partials, 40960, scal);
        finalize_k<<<640, 256, 0, stream>>>(stats, scal);
        gemm_k<0,0><<<dim3(6,2560), 256, 0, stream>>>(
            h, stats, n1_pre_g + i*128, n1_pre_b + i*128, n1_g + i*128, n1_b + i*128,
            nullptr, 0, Wq + (size_t)i*49152, 384, nullptr, buf, 0, nullptr, 128);
        attn_k<<<4096, 256, 0, stream>>>(buf, w_sigma + i);
        gemm_k<1,2><<<dim3(2,2560), 256, 0, stream>>>(
            nullptr, nullptr, nullptr, nullptr, nullptr, nullptr,
            bufu, 384, out_w + (size_t)i*16384, 128, out_b + i*128, nullptr, 0, h, 128);
        // ---- mln2 + FFN block ----
        mln_stats_k<<<40960, 256, 0, stream>>>(h, n2_pre_g + i*128, n2_pre_b + i*128, stats, partials);
        reduce_eps_k<<<1, 256, 0, stream>>>(partials, 40960, scal);
        finalize_k<<<640, 256, 0, stream>>>(stats, scal);
        gemm_k<0,1><<<dim3(8,2560), 256, 0, stream>>>(
            h, stats, n2_pre_g + i*128, n2_pre_b + i*128, n2_g + i*128, n2_b + i*128,
            nullptr, 0, ff_w1 + (size_t)i*65536, 512, ff_b1 + i*512, buf, 0, nullptr, 128);
        gemm_k<1,2><<<dim3(2,2560), 256, 0, stream>>>(
            nullptr, nullptr, nullptr, nullptr, nullptr, nullptr,
            bufu, 0, ff_w2 + (size_t)i*65536, 128, ff_b2 + i*128, nullptr, 0, h, 512);
    }

    // ---- final mln + head ----
    mln_stats_k<<<40960, 256, 0, stream>>>(h, fn_pre_g, fn_pre_b, stats, partials);
    reduce_eps_k<<<1, 256, 0, stream>>>(partials, 40960, scal);
    finalize_k<<<640, 256, 0, stream>>>(stats, scal);
    head_k<<<4096, 128, 0, stream>>>(h, stats, fn_pre_g, fn_pre_b, fn_g, fn_b,
                                     traj_w, traj_b, (float*)d_out);
}

// Round 5
// 1867.167 us; speedup vs baseline: 3.4726x; 2.6234x over previous
//
#include <hip/hip_runtime.h>
#include <hip/hip_bf16.h>

// Model dims (fixed)
#define DIMM 128
#define TT   40
#define BB   4096
#define NTOK (BB*TT)           // 163840
#define CHTOK (NTOK/2)         // 81920 tokens per chunk
#define NLAY 3

typedef float f4 __attribute__((ext_vector_type(4)));
typedef float f32x4 __attribute__((ext_vector_type(4)));
typedef short bf16x8 __attribute__((ext_vector_type(8)));

__device__ __forceinline__ float bf2f(unsigned short u) {
    union { unsigned int i; float f; } v; v.i = ((unsigned int)u) << 16; return v.f;
}
__device__ __forceinline__ unsigned short f2bu(float f) {
    __hip_bfloat16 h = __float2bfloat16(f);
    return *reinterpret_cast<unsigned short*>(&h);
}

// ---------------- pack ALL weights to bf16, transposed W^T[n][k] ----------------
__global__ __launch_bounds__(256) void pack_w_k(
    const float* __restrict__ qt, const float* __restrict__ kt,
    const float* __restrict__ qs, const float* __restrict__ ks,
    const float* __restrict__ vw, const float* __restrict__ ow,
    const float* __restrict__ w1, const float* __restrict__ w2,
    unsigned short* __restrict__ wqT, unsigned short* __restrict__ outT,
    unsigned short* __restrict__ ff1T, unsigned short* __restrict__ ff2T)
{
    int idx = blockIdx.x * 256 + threadIdx.x;          // 589824 total
    if (idx < 147456) {
        int i = idx / 49152, r = idx % 49152;
        int n = r / 128, k = r % 128;
        float v;
        if (n < 32)        v = qt[i*4096  + k*32  + n];
        else if (n < 64)   v = kt[i*4096  + k*32  + (n-32)];
        else if (n < 160)  v = qs[i*12288 + k*96  + (n-64)];
        else if (n < 256)  v = ks[i*12288 + k*96  + (n-160)];
        else               v = vw[i*16384 + k*128 + (n-256)];
        wqT[idx] = f2bu(v);
    } else if (idx < 196608) {
        int j = idx - 147456;
        int i = j / 16384, r = j % 16384;
        int n = r / 128, k = r % 128;
        outT[j] = f2bu(ow[i*16384 + k*128 + n]);
    } else if (idx < 393216) {
        int j = idx - 196608;
        int i = j / 65536, r = j % 65536;
        int n = r / 128, k = r % 128;
        ff1T[j] = f2bu(w1[i*65536 + k*512 + n]);
    } else {
        int j = idx - 393216;
        int i = j / 65536, r = j % 65536;
        int n = r / 512, k = r % 512;
        ff2T[j] = f2bu(w2[i*65536 + k*128 + n]);
    }
}

// ---------------- embedding: h = x @ embed_w + embed_b + pos ----------------
__global__ __launch_bounds__(256) void embed_k(
    const float* __restrict__ x, const float* __restrict__ ew,
    const float* __restrict__ eb, const float* __restrict__ pos,
    float* __restrict__ h)
{
    int idx = blockIdx.x * 256 + threadIdx.x;      // NTOK*128
    int n = idx >> 7, d = idx & 127;
    int t = n % TT;
    const float* xr = x + (size_t)n * 6;
    float acc = eb[d] + pos[t*128 + d];
    #pragma unroll
    for (int k = 0; k < 6; ++k) acc += xr[k] * ew[k*128 + d];
    h[idx] = acc;
}

// ---------------- mln stats: per token mean, rstd, mq; block partial of |mq| ----------------
__global__ __launch_bounds__(256) void mln_stats_k(
    const float* __restrict__ h, const float* __restrict__ pg, const float* __restrict__ pb,
    float* __restrict__ stats, float* __restrict__ partials)
{
    int wid = threadIdx.x >> 6, lane = threadIdx.x & 63;
    int tok = blockIdx.x * 4 + wid;
    const float* hr = h + (size_t)tok * 128;
    float x0 = hr[lane], x1 = hr[lane + 64];
    float s = x0 + x1;
    #pragma unroll
    for (int o = 32; o > 0; o >>= 1) s += __shfl_xor(s, o);
    float m = s * (1.f / 128.f);
    float d0 = x0 - m, d1 = x1 - m;
    float v = d0*d0 + d1*d1;
    #pragma unroll
    for (int o = 32; o > 0; o >>= 1) v += __shfl_xor(v, o);
    float rstd = rsqrtf(v * (1.f / 128.f) + 1e-5f);
    float y0 = d0 * rstd * pg[lane]      + pb[lane];
    float y1 = d1 * rstd * pg[lane + 64] + pb[lane + 64];
    // dims 0..31 are "t" (negative), 32..127 are "s" (positive)
    float q = (lane < 32 ? -(y0*y0) : (y0*y0)) + y1*y1;
    #pragma unroll
    for (int o = 32; o > 0; o >>= 1) q += __shfl_xor(q, o);
    if (lane == 0) {
        stats[(size_t)tok*4 + 0] = m;
        stats[(size_t)tok*4 + 1] = rstd;
        stats[(size_t)tok*4 + 2] = q;
    }
    __shared__ float pm[4];
    if (lane == 0) pm[wid] = fabsf(q);
    __syncthreads();
    if (threadIdx.x == 0) partials[blockIdx.x] = (pm[0] + pm[1]) + (pm[2] + pm[3]);
}

// ---------------- reduce partials -> eps scalar (deterministic) ----------------
__global__ __launch_bounds__(256) void reduce_eps_k(
    const float* __restrict__ partials, int n, float* __restrict__ scal)
{
    float s = 0.f;
    for (int i = threadIdx.x; i < n; i += 256) s += partials[i];
    __shared__ float sm[256];
    sm[threadIdx.x] = s;
    __syncthreads();
    for (int o = 128; o > 0; o >>= 1) {
        if (threadIdx.x < o) sm[threadIdx.x] += sm[threadIdx.x + o];
        __syncthreads();
    }
    if (threadIdx.x == 0) {
        float mean = sm[0] / (float)NTOK;
        scal[0] = fmaxf(0.01f * mean, 1e-5f);
    }
}

// ---------------- apply mln: y = g*(ln(x)*s3)+b  -> bf16 ----------------
__global__ __launch_bounds__(256) void mln_apply_k(
    const float* __restrict__ h, const float* __restrict__ stats, const float* __restrict__ scal,
    const float* __restrict__ pg, const float* __restrict__ pb,
    const float* __restrict__ gg, const float* __restrict__ gb,
    unsigned short* __restrict__ y)
{
    int gid = blockIdx.x * 256 + threadIdx.x;      // NTOK*32
    int tok = gid >> 5, c4 = (gid & 31) << 2;
    float eps = scal[0];
    float m  = stats[(size_t)tok*4 + 0];
    float rs = stats[(size_t)tok*4 + 1];
    float mq = stats[(size_t)tok*4 + 2];
    float s3 = 1.f / (sqrtf(fabsf(mq) + eps) + eps);
    f4 x = *(const f4*)(h + (size_t)tok*128 + c4);
    ushort4 o;
    float v0 = gg[c4+0] * (((x[0]-m)*rs*pg[c4+0] + pb[c4+0]) * s3) + gb[c4+0];
    float v1 = gg[c4+1] * (((x[1]-m)*rs*pg[c4+1] + pb[c4+1]) * s3) + gb[c4+1];
    float v2 = gg[c4+2] * (((x[2]-m)*rs*pg[c4+2] + pb[c4+2]) * s3) + gb[c4+2];
    float v3 = gg[c4+3] * (((x[3]-m)*rs*pg[c4+3] + pb[c4+3]) * s3) + gb[c4+3];
    o.x = f2bu(v0); o.y = f2bu(v1); o.z = f2bu(v2); o.w = f2bu(v3);
    *(ushort4*)(y + (size_t)tok*128 + c4) = o;
}

// ---------------- MFMA GEMM: C[M x N] = A[M x K](bf16) @ B(bf16, stored B^T[n][k]) ----------------
// tile 128x64, 4 waves, each wave 64x32 via mfma_f32_16x16x32_bf16
// EPI 0: bf16 store (+bias if non-null); EPI 1: gelu(v+bias)->bf16; EPI 2: hres += v+bias
#define LDS_A_STRIDE 272     // 128 bf16 + 8 pad  (17*16B, 16B aligned)
template<int EPI>
__global__ __launch_bounds__(256) void mgemm_k(
    const unsigned short* __restrict__ A, int lda,
    const unsigned short* __restrict__ BT,            // [N][K] bf16
    const float* __restrict__ bias,
    unsigned short* __restrict__ obuf, int ldo,
    float* __restrict__ hres, int K)
{
    __shared__ unsigned char lds[192*LDS_A_STRIDE];   // A (128 rows) then B (64 rows): 52224 B
    unsigned char* AsB = lds;
    unsigned char* BsB = lds + 128*LDS_A_STRIDE;

    const int tid = threadIdx.x;
    const int wid = tid >> 6, lane = tid & 63;
    const int wr = wid >> 1, wc = wid & 1;
    const int row0 = blockIdx.y * 128, col0 = blockIdx.x * 64;

    f32x4 acc[4][2] = {};

    for (int kk = 0; kk < K; kk += 128) {
        __syncthreads();
        // ---- stage A: 128 rows x 128 k ----
        {
            int row = tid >> 4, q8 = (tid & 15) << 3;
            #pragma unroll
            for (int p = 0; p < 8; ++p, row += 16) {
                uint4 av = *(const uint4*)(A + (size_t)(row0 + row)*lda + kk + q8);
                *(uint4*)(AsB + row*LDS_A_STRIDE + q8*2) = av;
            }
        }
        // ---- stage B: 64 cols x 128 k ----
        {
            int col = tid >> 4, q8 = (tid & 15) << 3;
            #pragma unroll
            for (int p = 0; p < 4; ++p, col += 16) {
                uint4 bv = *(const uint4*)(BT + (size_t)(col0 + col)*K + kk + q8);
                *(uint4*)(BsB + col*LDS_A_STRIDE + q8*2) = bv;
            }
        }
        __syncthreads();
        // ---- compute: 4 k-steps of 32 ----
        #pragma unroll
        for (int ks = 0; ks < 4; ++ks) {
            int kb = ks*64 + ((lane >> 4) << 4);       // byte offset: ks*32 bf16 + (lane>>4)*8 bf16
            bf16x8 a[4], b[2];
            #pragma unroll
            for (int m = 0; m < 4; ++m)
                a[m] = *(const bf16x8*)(AsB + (wr*64 + m*16 + (lane & 15))*LDS_A_STRIDE + kb);
            #pragma unroll
            for (int n = 0; n < 2; ++n)
                b[n] = *(const bf16x8*)(BsB + (wc*32 + n*16 + (lane & 15))*LDS_A_STRIDE + kb);
            #pragma unroll
            for (int m = 0; m < 4; ++m)
                #pragma unroll
                for (int n = 0; n < 2; ++n)
                    acc[m][n] = __builtin_amdgcn_mfma_f32_16x16x32_bf16(a[m], b[n], acc[m][n], 0, 0, 0);
        }
    }
    // ---- epilogue ----
    const int rb = row0 + wr*64 + ((lane >> 4) << 2);
    const int cb = col0 + wc*32 + (lane & 15);
    #pragma unroll
    for (int n = 0; n < 2; ++n) {
        int col = cb + n*16;
        float bv = bias ? bias[col] : 0.f;
        #pragma unroll
        for (int m = 0; m < 4; ++m) {
            #pragma unroll
            for (int r = 0; r < 4; ++r) {
                int row = rb + m*16 + r;
                float v = acc[m][n][r] + bv;
                if (EPI == 1) v = 0.5f * v * (1.f + erff(v * 0.70710678118654752f));
                if (EPI <= 1) obuf[(size_t)row*ldo + col] = f2bu(v);
                else          hres[(size_t)row*128 + col] += v;
            }
        }
    }
}

// ---------------- attention: block per (chunk-local) batch, THREAD per (head, query) ----------------
// reads qkv (ld 384: qt 0-31 | kt 32-63 | qs 64-159 | ks 160-255 | v 256-383)
// writes attn output (pre out-proj) into yout (ld 128), overwriting consumed mln rows
__global__ __launch_bounds__(256) void attn_k(
    const unsigned short* __restrict__ qkv,
    unsigned short* __restrict__ yout,
    const float* __restrict__ wsp)
{
    __shared__ float Kl[4][40][32];
    __shared__ float Vl[4][40][32];
    int b = blockIdx.x;
    int tid = threadIdx.x;

    for (int e = tid; e < 1280; e += 256) {
        int r = e >> 3, q4 = (e & 7) << 2;
        int h = r / 40, t = r - h * 40;
        const unsigned short* src = qkv + (size_t)(b*TT + t) * 384;
        int kcol = (h == 0) ? 32 : 128 + h*32;
        ushort4 uk = *(const ushort4*)(src + kcol + q4);
        ushort4 uv = *(const ushort4*)(src + 256 + h*32 + q4);
        f4 fk, fv;
        fk[0]=bf2f(uk.x); fk[1]=bf2f(uk.y); fk[2]=bf2f(uk.z); fk[3]=bf2f(uk.w);
        fv[0]=bf2f(uv.x); fv[1]=bf2f(uv.y); fv[2]=bf2f(uv.z); fv[3]=bf2f(uv.w);
        *(f4*)(&Kl[h][t][q4]) = fk;
        *(f4*)(&Vl[h][t][q4]) = fv;
    }
    __syncthreads();
    if (tid >= 160) return;

    int h = tid / 40, t = tid - h * 40;
    const unsigned short* qrow = qkv + (size_t)(b*TT + t) * 384;
    int qcol = (h == 0) ? 0 : 32 + h*32;

    float q[32];
    #pragma unroll
    for (int k = 0; k < 32; k += 4) {
        ushort4 u = *(const ushort4*)(qrow + qcol + k);
        q[k]=bf2f(u.x); q[k+1]=bf2f(u.y); q[k+2]=bf2f(u.z); q[k+3]=bf2f(u.w);
    }
    const float scale = 0.17677669529663687f;   // 32^-0.5
    float wmul = scale;
    if (h == 0) wmul = -scale / (1.f + __expf(-wsp[0]));

    float sc[40];
    float mx = -1e30f;
    #pragma unroll
    for (int s = 0; s < 40; ++s) {
        float dot = 0.f;
        #pragma unroll
        for (int k = 0; k < 32; k += 4) {
            const f4 kv = *(const f4*)(&Kl[h][s][k]);
            dot += q[k]*kv[0] + q[k+1]*kv[1] + q[k+2]*kv[2] + q[k+3]*kv[3];
        }
        float v = wmul * dot;
        sc[s] = v;
        mx = fmaxf(mx, v);
    }
    float sum = 0.f;
    #pragma unroll
    for (int s = 0; s < 40; ++s) { float p = __expf(sc[s] - mx); sc[s] = p; sum += p; }
    float inv = 1.f / sum;

    float acc[32] = {};
    #pragma unroll
    for (int s = 0; s < 40; ++s) {
        float p = sc[s];
        #pragma unroll
        for (int k = 0; k < 32; k += 4) {
            const f4 vv = *(const f4*)(&Vl[h][s][k]);
            acc[k]   += p*vv[0]; acc[k+1] += p*vv[1];
            acc[k+2] += p*vv[2]; acc[k+3] += p*vv[3];
        }
    }
    unsigned short* orow = yout + (size_t)(b*TT + t) * 128 + h*32;
    #pragma unroll
    for (int k = 0; k < 32; k += 4) {
        ushort4 u;
        u.x = f2bu(acc[k]  *inv); u.y = f2bu(acc[k+1]*inv);
        u.z = f2bu(acc[k+2]*inv); u.w = f2bu(acc[k+3]*inv);
        *(ushort4*)(orow + k) = u;
    }
}

// ---------------- head: last token y (bf16) @ traj_w + traj_b (f32 out) ----------------
__global__ __launch_bounds__(128) void head_k(
    const unsigned short* __restrict__ y,
    const float* __restrict__ tw, const float* __restrict__ tb,
    float* __restrict__ out)
{
    int b = blockIdx.x, tid = threadIdx.x;
    int tok = b*TT + (TT - 1);
    __shared__ float ys[128];
    ys[tid] = bf2f(y[(size_t)tok*128 + tid]);
    __syncthreads();
    if (tid < 120) {
        float acc = tb[tid];
        #pragma unroll 4
        for (int d = 0; d < 128; ++d) acc += ys[d] * tw[d*120 + tid];
        out[(size_t)b*120 + tid] = acc;
    }
}

extern "C" void kernel_launch(void* const* d_in, const int* in_sizes, int n_in,
                              void* d_out, int out_size, void* d_ws, size_t ws_size,
                              hipStream_t stream) {
    const float* x        = (const float*)d_in[0];
    const float* embed_w  = (const float*)d_in[1];
    const float* embed_b  = (const float*)d_in[2];
    const float* pos      = (const float*)d_in[3];
    const float* qt_w     = (const float*)d_in[4];
    const float* kt_w     = (const float*)d_in[5];
    const float* qs_w     = (const float*)d_in[6];
    const float* ks_w     = (const float*)d_in[7];
    const float* v_w      = (const float*)d_in[8];
    const float* out_w    = (const float*)d_in[9];
    const float* out_b    = (const float*)d_in[10];
    const float* w_sigma  = (const float*)d_in[11];
    const float* n1_pre_g = (const float*)d_in[12];
    const float* n1_pre_b = (const float*)d_in[13];
    const float* n1_g     = (const float*)d_in[14];
    const float* n1_b     = (const float*)d_in[15];
    const float* n2_pre_g = (const float*)d_in[16];
    const float* n2_pre_b = (const float*)d_in[17];
    const float* n2_g     = (const float*)d_in[18];
    const float* n2_b     = (const float*)d_in[19];
    const float* ff_w1    = (const float*)d_in[20];
    const float* ff_b1    = (const float*)d_in[21];
    const float* ff_w2    = (const float*)d_in[22];
    const float* ff_b2    = (const float*)d_in[23];
    const float* fn_pre_g = (const float*)d_in[24];
    const float* fn_pre_b = (const float*)d_in[25];
    const float* fn_g     = (const float*)d_in[26];
    const float* fn_b     = (const float*)d_in[27];
    const float* traj_w   = (const float*)d_in[28];
    const float* traj_b   = (const float*)d_in[29];

    // ---- workspace layout (total 213,680,640 B < 255 MB proven-good) ----
    char* ws = (char*)d_ws;
    float*          h       = (float*)ws;                           //  83,886,080 B
    float*          stats   = (float*)(ws + 83886080);              //   2,621,440 B
    unsigned short* y       = (unsigned short*)(ws + 86507520);     //  41,943,040 B (NTOK x 128 bf16)
    unsigned short* scratch = (unsigned short*)(ws + 128450560);    //  83,886,080 B (CHTOK x 512 bf16)
    unsigned short* wqT     = (unsigned short*)(ws + 212336640);    //     294,912 B
    unsigned short* outT    = (unsigned short*)(ws + 212631552);    //      98,304 B
    unsigned short* ff1T    = (unsigned short*)(ws + 212729856);    //     393,216 B
    unsigned short* ff2T    = (unsigned short*)(ws + 213123072);    //     393,216 B
    float*          partials= (float*)(ws + 213516288);             //     163,840 B
    float*          scal    = (float*)(ws + 213680128);             //         256 B

    pack_w_k<<<2304, 256, 0, stream>>>(qt_w, kt_w, qs_w, ks_w, v_w, out_w, ff_w1, ff_w2,
                                       wqT, outT, ff1T, ff2T);
    embed_k<<<81920, 256, 0, stream>>>(x, embed_w, embed_b, pos, h);

    for (int i = 0; i < NLAY; ++i) {
        // ---- mln1 + attention block ----
        mln_stats_k<<<40960, 256, 0, stream>>>(h, n1_pre_g + i*128, n1_pre_b + i*128, stats, partials);
        reduce_eps_k<<<1, 256, 0, stream>>>(partials, 40960, scal);
        mln_apply_k<<<20480, 256, 0, stream>>>(h, stats, scal, n1_pre_g + i*128, n1_pre_b + i*128,
                                               n1_g + i*128, n1_b + i*128, y);
        for (int c = 0; c < 2; ++c) {
            size_t off = (size_t)c * CHTOK;
            mgemm_k<0><<<dim3(6, 640), 256, 0, stream>>>(
                y + off*128, 128, wqT + (size_t)i*49152, nullptr, scratch, 384, nullptr, 128);
            attn_k<<<2048, 256, 0, stream>>>(scratch, y + off*128, w_sigma + i);
            mgemm_k<2><<<dim3(2, 640), 256, 0, stream>>>(
                y + off*128, 128, outT + (size_t)i*16384, out_b + i*128, nullptr, 0, h + off*128, 128);
        }
        // ---- mln2 + FFN block ----
        mln_stats_k<<<40960, 256, 0, stream>>>(h, n2_pre_g + i*128, n2_pre_b + i*128, stats, partials);
        reduce_eps_k<<<1, 256, 0, stream>>>(partials, 40960, scal);
        mln_apply_k<<<20480, 256, 0, stream>>>(h, stats, scal, n2_pre_g + i*128, n2_pre_b + i*128,
                                               n2_g + i*128, n2_b + i*128, y);
        for (int c = 0; c < 2; ++c) {
            size_t off = (size_t)c * CHTOK;
            mgemm_k<1><<<dim3(8, 640), 256, 0, stream>>>(
                y + off*128, 128, ff1T + (size_t)i*65536, ff_b1 + i*512, scratch, 512, nullptr, 128);
            mgemm_k<2><<<dim3(2, 640), 256, 0, stream>>>(
                scratch, 512, ff2T + (size_t)i*65536, ff_b2 + i*128, nullptr, 0, h + off*128, 512);
        }
    }

    // ---- final mln + head ----
    mln_stats_k<<<40960, 256, 0, stream>>>(h, fn_pre_g, fn_pre_b, stats, partials);
    reduce_eps_k<<<1, 256, 0, stream>>>(partials, 40960, scal);
    mln_apply_k<<<20480, 256, 0, stream>>>(h, stats, scal, fn_pre_g, fn_pre_b, fn_g, fn_b, y);
    head_k<<<4096, 128, 0, stream>>>(y, traj_w, traj_b, (float*)d_out);
}

// Round 6
// 1799.981 us; speedup vs baseline: 3.6022x; 1.0373x over previous
//
#include <hip/hip_runtime.h>
#include <hip/hip_bf16.h>

// Model dims (fixed)
#define DIMM 128
#define TT   40
#define BB   4096
#define NTOK (BB*TT)           // 163840
#define CHTOK (NTOK/2)         // 81920 tokens per chunk (qkv scratch)
#define NLAY 3

typedef float f4 __attribute__((ext_vector_type(4)));
typedef float f32x4 __attribute__((ext_vector_type(4)));
typedef short bf16x8 __attribute__((ext_vector_type(8)));

__device__ __forceinline__ float bf2f(unsigned short u) {
    union { unsigned int i; float f; } v; v.i = ((unsigned int)u) << 16; return v.f;
}
__device__ __forceinline__ unsigned short f2bu(float f) {
    __hip_bfloat16 h = __float2bfloat16(f);
    return *reinterpret_cast<unsigned short*>(&h);
}

// ---------------- pack ALL weights to bf16, transposed W^T[n][k] ----------------
__global__ __launch_bounds__(256) void pack_w_k(
    const float* __restrict__ qt, const float* __restrict__ kt,
    const float* __restrict__ qs, const float* __restrict__ ks,
    const float* __restrict__ vw, const float* __restrict__ ow,
    const float* __restrict__ w1, const float* __restrict__ w2,
    unsigned short* __restrict__ wqT, unsigned short* __restrict__ outT,
    unsigned short* __restrict__ ff1T, unsigned short* __restrict__ ff2T)
{
    int idx = blockIdx.x * 256 + threadIdx.x;          // 589824 total
    if (idx < 147456) {
        int i = idx / 49152, r = idx % 49152;
        int n = r / 128, k = r % 128;
        float v;
        if (n < 32)        v = qt[i*4096  + k*32  + n];
        else if (n < 64)   v = kt[i*4096  + k*32  + (n-32)];
        else if (n < 160)  v = qs[i*12288 + k*96  + (n-64)];
        else if (n < 256)  v = ks[i*12288 + k*96  + (n-160)];
        else               v = vw[i*16384 + k*128 + (n-256)];
        wqT[idx] = f2bu(v);
    } else if (idx < 196608) {
        int j = idx - 147456;
        int i = j / 16384, r = j % 16384;
        int n = r / 128, k = r % 128;
        outT[j] = f2bu(ow[i*16384 + k*128 + n]);
    } else if (idx < 393216) {
        int j = idx - 196608;
        int i = j / 65536, r = j % 65536;
        int n = r / 128, k = r % 128;
        ff1T[j] = f2bu(w1[i*65536 + k*512 + n]);
    } else {
        int j = idx - 393216;
        int i = j / 65536, r = j % 65536;
        int n = r / 512, k = r % 512;
        ff2T[j] = f2bu(w2[i*65536 + k*128 + n]);
    }
}

// ---------------- embedding: h = x @ embed_w + embed_b + pos ----------------
__global__ __launch_bounds__(256) void embed_k(
    const float* __restrict__ x, const float* __restrict__ ew,
    const float* __restrict__ eb, const float* __restrict__ pos,
    float* __restrict__ h)
{
    int idx = blockIdx.x * 256 + threadIdx.x;      // NTOK*128
    int n = idx >> 7, d = idx & 127;
    int t = n % TT;
    const float* xr = x + (size_t)n * 6;
    float acc = eb[d] + pos[t*128 + d];
    #pragma unroll
    for (int k = 0; k < 6; ++k) acc += xr[k] * ew[k*128 + d];
    h[idx] = acc;
}

// ---------------- mln stats: per token mean, rstd, mq; block partial of |mq| ----------------
__global__ __launch_bounds__(256) void mln_stats_k(
    const float* __restrict__ h, const float* __restrict__ pg, const float* __restrict__ pb,
    float* __restrict__ stats, float* __restrict__ partials)
{
    int wid = threadIdx.x >> 6, lane = threadIdx.x & 63;
    int tok = blockIdx.x * 4 + wid;
    const float* hr = h + (size_t)tok * 128;
    float x0 = hr[lane], x1 = hr[lane + 64];
    float s = x0 + x1;
    #pragma unroll
    for (int o = 32; o > 0; o >>= 1) s += __shfl_xor(s, o);
    float m = s * (1.f / 128.f);
    float d0 = x0 - m, d1 = x1 - m;
    float v = d0*d0 + d1*d1;
    #pragma unroll
    for (int o = 32; o > 0; o >>= 1) v += __shfl_xor(v, o);
    float rstd = rsqrtf(v * (1.f / 128.f) + 1e-5f);
    float y0 = d0 * rstd * pg[lane]      + pb[lane];
    float y1 = d1 * rstd * pg[lane + 64] + pb[lane + 64];
    // dims 0..31 are "t" (negative), 32..127 are "s" (positive)
    float q = (lane < 32 ? -(y0*y0) : (y0*y0)) + y1*y1;
    #pragma unroll
    for (int o = 32; o > 0; o >>= 1) q += __shfl_xor(q, o);
    if (lane == 0) {
        stats[(size_t)tok*4 + 0] = m;
        stats[(size_t)tok*4 + 1] = rstd;
        stats[(size_t)tok*4 + 2] = q;
    }
    __shared__ float pm[4];
    if (lane == 0) pm[wid] = fabsf(q);
    __syncthreads();
    if (threadIdx.x == 0) partials[blockIdx.x] = (pm[0] + pm[1]) + (pm[2] + pm[3]);
}

// ---------------- reduce partials -> eps scalar (deterministic) ----------------
__global__ __launch_bounds__(1024) void reduce_eps_k(
    const float* __restrict__ partials, int n, float* __restrict__ scal)
{
    float s = 0.f;
    for (int i = threadIdx.x; i < n; i += 1024) s += partials[i];
    __shared__ float sm[1024];
    sm[threadIdx.x] = s;
    __syncthreads();
    for (int o = 512; o > 0; o >>= 1) {
        if (threadIdx.x < o) sm[threadIdx.x] += sm[threadIdx.x + o];
        __syncthreads();
    }
    if (threadIdx.x == 0) {
        float mean = sm[0] / (float)NTOK;
        scal[0] = fmaxf(0.01f * mean, 1e-5f);
    }
}

// ---------------- apply mln: y = g*(ln(x)*s3)+b  -> bf16 ----------------
__global__ __launch_bounds__(256) void mln_apply_k(
    const float* __restrict__ h, const float* __restrict__ stats, const float* __restrict__ scal,
    const float* __restrict__ pg, const float* __restrict__ pb,
    const float* __restrict__ gg, const float* __restrict__ gb,
    unsigned short* __restrict__ y)
{
    int gid = blockIdx.x * 256 + threadIdx.x;      // NTOK*32
    int tok = gid >> 5, c4 = (gid & 31) << 2;
    float eps = scal[0];
    float m  = stats[(size_t)tok*4 + 0];
    float rs = stats[(size_t)tok*4 + 1];
    float mq = stats[(size_t)tok*4 + 2];
    float s3 = 1.f / (sqrtf(fabsf(mq) + eps) + eps);
    f4 x = *(const f4*)(h + (size_t)tok*128 + c4);
    ushort4 o;
    float v0 = gg[c4+0] * (((x[0]-m)*rs*pg[c4+0] + pb[c4+0]) * s3) + gb[c4+0];
    float v1 = gg[c4+1] * (((x[1]-m)*rs*pg[c4+1] + pb[c4+1]) * s3) + gb[c4+1];
    float v2 = gg[c4+2] * (((x[2]-m)*rs*pg[c4+2] + pb[c4+2]) * s3) + gb[c4+2];
    float v3 = gg[c4+3] * (((x[3]-m)*rs*pg[c4+3] + pb[c4+3]) * s3) + gb[c4+3];
    o.x = f2bu(v0); o.y = f2bu(v1); o.z = f2bu(v2); o.w = f2bu(v3);
    *(ushort4*)(y + (size_t)tok*128 + c4) = o;
}

// ---------------- MFMA GEMM: C[M x N] = A[M x K](bf16) @ B(bf16, stored B^T[n][k]) ----------------
// tile 128x64, 4 waves, each wave 64x32 via mfma_f32_16x16x32_bf16
// EPI 0: bf16 store (+bias if non-null); EPI 2: hres += v+bias
#define LDS_A_STRIDE 272     // 128 bf16 + 8 pad  (17*16B, 16B aligned)
template<int EPI>
__global__ __launch_bounds__(256) void mgemm_k(
    const unsigned short* __restrict__ A, int lda,
    const unsigned short* __restrict__ BT,            // [N][K] bf16
    const float* __restrict__ bias,
    unsigned short* __restrict__ obuf, int ldo,
    float* __restrict__ hres, int K)
{
    __shared__ unsigned char lds[192*LDS_A_STRIDE];   // A (128 rows) then B (64 rows)
    unsigned char* AsB = lds;
    unsigned char* BsB = lds + 128*LDS_A_STRIDE;

    const int tid = threadIdx.x;
    const int wid = tid >> 6, lane = tid & 63;
    const int wr = wid >> 1, wc = wid & 1;
    const int row0 = blockIdx.y * 128, col0 = blockIdx.x * 64;

    f32x4 acc[4][2] = {};

    for (int kk = 0; kk < K; kk += 128) {
        __syncthreads();
        {
            int row = tid >> 4, q8 = (tid & 15) << 3;
            #pragma unroll
            for (int p = 0; p < 8; ++p, row += 16) {
                uint4 av = *(const uint4*)(A + (size_t)(row0 + row)*lda + kk + q8);
                *(uint4*)(AsB + row*LDS_A_STRIDE + q8*2) = av;
            }
        }
        {
            int col = tid >> 4, q8 = (tid & 15) << 3;
            #pragma unroll
            for (int p = 0; p < 4; ++p, col += 16) {
                uint4 bv = *(const uint4*)(BT + (size_t)(col0 + col)*K + kk + q8);
                *(uint4*)(BsB + col*LDS_A_STRIDE + q8*2) = bv;
            }
        }
        __syncthreads();
        #pragma unroll
        for (int ks = 0; ks < 4; ++ks) {
            int kb = ks*64 + ((lane >> 4) << 4);
            bf16x8 a[4], b[2];
            #pragma unroll
            for (int m = 0; m < 4; ++m)
                a[m] = *(const bf16x8*)(AsB + (wr*64 + m*16 + (lane & 15))*LDS_A_STRIDE + kb);
            #pragma unroll
            for (int n = 0; n < 2; ++n)
                b[n] = *(const bf16x8*)(BsB + (wc*32 + n*16 + (lane & 15))*LDS_A_STRIDE + kb);
            #pragma unroll
            for (int m = 0; m < 4; ++m)
                #pragma unroll
                for (int n = 0; n < 2; ++n)
                    acc[m][n] = __builtin_amdgcn_mfma_f32_16x16x32_bf16(a[m], b[n], acc[m][n], 0, 0, 0);
        }
    }
    const int rb = row0 + wr*64 + ((lane >> 4) << 2);
    const int cb = col0 + wc*32 + (lane & 15);
    #pragma unroll
    for (int n = 0; n < 2; ++n) {
        int col = cb + n*16;
        float bv = bias ? bias[col] : 0.f;
        #pragma unroll
        for (int m = 0; m < 4; ++m) {
            #pragma unroll
            for (int r = 0; r < 4; ++r) {
                int row = rb + m*16 + r;
                float v = acc[m][n][r] + bv;
                if (EPI == 0) obuf[(size_t)row*ldo + col] = f2bu(v);
                else          hres[(size_t)row*128 + col] += v;
            }
        }
    }
}

// ---------------- fused FFN: h += gelu(y@W1+b1)@W2 + b2 ----------------
// 128-row tile per block, 4 waves, mid (512) looped in chunks of 64 (P in wave-private LDS rows)
__global__ __launch_bounds__(256, 3) void ffn_k(
    const unsigned short* __restrict__ y,     // [NTOK][128] bf16
    const unsigned short* __restrict__ W1T,   // [512][128] bf16
    const float* __restrict__ b1,             // [512]
    const unsigned short* __restrict__ W2T,   // [128][512] bf16
    const float* __restrict__ b2,             // [128]
    float* __restrict__ h)                    // [NTOK][128] f32, +=
{
    __shared__ unsigned char As[128*272];     // y tile, stride 272B
    __shared__ unsigned char Ps[128*144];     // gelu mid chunk, stride 144B (bank-rotating)
    const int tid = threadIdx.x;
    const int wid = tid >> 6, lane = tid & 63;
    const int q = lane >> 4, l15 = lane & 15;
    const int row0 = blockIdx.x * 128;
    const int wrow = wid * 32;

    {
        int row = tid >> 4, q8 = (tid & 15) << 3;
        #pragma unroll
        for (int p = 0; p < 8; ++p, row += 16) {
            uint4 av = *(const uint4*)(y + (size_t)(row0 + row)*128 + q8);
            *(uint4*)(As + row*272 + q8*2) = av;
        }
    }
    __syncthreads();

    float b2v[8];
    #pragma unroll
    for (int nf = 0; nf < 8; ++nf) b2v[nf] = b2[nf*16 + l15];

    f32x4 acc2[2][8] = {};

    for (int c = 0; c < 8; ++c) {
        // ---- gemm1: P = y_tile @ W1[:, 64c:64c+64] ----
        f32x4 acc1[2][4] = {};
        #pragma unroll
        for (int ks = 0; ks < 4; ++ks) {
            bf16x8 a[2];
            #pragma unroll
            for (int mf = 0; mf < 2; ++mf)
                a[mf] = *(const bf16x8*)(As + (wrow + mf*16 + l15)*272 + ks*64 + q*16);
            #pragma unroll
            for (int nf = 0; nf < 4; ++nf) {
                bf16x8 b = *(const bf16x8*)(W1T + (size_t)(c*64 + nf*16 + l15)*128 + ks*32 + q*8);
                #pragma unroll
                for (int mf = 0; mf < 2; ++mf)
                    acc1[mf][nf] = __builtin_amdgcn_mfma_f32_16x16x32_bf16(a[mf], b, acc1[mf][nf], 0, 0, 0);
            }
        }
        // ---- bias + exact gelu -> Ps (wave-private rows; no cross-wave dep) ----
        #pragma unroll
        for (int nf = 0; nf < 4; ++nf) {
            float bb = b1[c*64 + nf*16 + l15];
            #pragma unroll
            for (int mf = 0; mf < 2; ++mf) {
                #pragma unroll
                for (int r = 0; r < 4; ++r) {
                    float v = acc1[mf][nf][r] + bb;
                    v = 0.5f * v * (1.f + erff(v * 0.70710678118654752f));
                    int prow = wrow + mf*16 + q*4 + r;
                    *(unsigned short*)(Ps + prow*144 + (nf*16 + l15)*2) = f2bu(v);
                }
            }
        }
        // ---- gemm2: acc2 += gelu_mid @ W2[64c:64c+64, :] ----
        #pragma unroll
        for (int ks2 = 0; ks2 < 2; ++ks2) {
            bf16x8 a2[2];
            #pragma unroll
            for (int mf = 0; mf < 2; ++mf)
                a2[mf] = *(const bf16x8*)(Ps + (wrow + mf*16 + l15)*144 + ks2*64 + q*16);
            #pragma unroll
            for (int nf = 0; nf < 8; ++nf) {
                bf16x8 b = *(const bf16x8*)(W2T + (size_t)(nf*16 + l15)*512 + c*64 + ks2*32 + q*8);
                #pragma unroll
                for (int mf = 0; mf < 2; ++mf)
                    acc2[mf][nf] = __builtin_amdgcn_mfma_f32_16x16x32_bf16(a2[mf], b, acc2[mf][nf], 0, 0, 0);
            }
        }
    }
    // ---- epilogue: h += acc2 + b2 ----
    #pragma unroll
    for (int mf = 0; mf < 2; ++mf) {
        #pragma unroll
        for (int r = 0; r < 4; ++r) {
            int row = row0 + wrow + mf*16 + q*4 + r;
            float* hr = h + (size_t)row*128;
            #pragma unroll
            for (int nf = 0; nf < 8; ++nf)
                hr[nf*16 + l15] += acc2[mf][nf][r] + b2v[nf];
        }
    }
}

// ---------------- attention: block per (chunk-local) batch, THREAD per (head, query) ----------------
// qkv ld 384: qt 0-31 | kt 32-63 | qs 64-159 | ks 160-255 | v 256-383
// K/V LDS columns XOR-swizzled by h<<2 so the 2-4 h-groups in a wave hit distinct banks
__global__ __launch_bounds__(256) void attn_k(
    const unsigned short* __restrict__ qkv,
    unsigned short* __restrict__ yout,
    const float* __restrict__ wsp)
{
    __shared__ float Kl[4][40][32];
    __shared__ float Vl[4][40][32];
    int b = blockIdx.x;
    int tid = threadIdx.x;

    for (int e = tid; e < 1280; e += 256) {
        int r = e >> 3, q4 = (e & 7) << 2;
        int h = r / 40, t = r - h * 40;
        int hx = h << 2;
        const unsigned short* src = qkv + (size_t)(b*TT + t) * 384;
        int kcol = (h == 0) ? 32 : 128 + h*32;
        ushort4 uk = *(const ushort4*)(src + kcol + q4);
        ushort4 uv = *(const ushort4*)(src + 256 + h*32 + q4);
        f4 fk, fv;
        fk[0]=bf2f(uk.x); fk[1]=bf2f(uk.y); fk[2]=bf2f(uk.z); fk[3]=bf2f(uk.w);
        fv[0]=bf2f(uv.x); fv[1]=bf2f(uv.y); fv[2]=bf2f(uv.z); fv[3]=bf2f(uv.w);
        *(f4*)(&Kl[h][t][q4 ^ hx]) = fk;
        *(f4*)(&Vl[h][t][q4 ^ hx]) = fv;
    }
    __syncthreads();
    if (tid >= 160) return;

    int h = tid / 40, t = tid - h * 40;
    int hx = h << 2;
    const unsigned short* qrow = qkv + (size_t)(b*TT + t) * 384;
    int qcol = (h == 0) ? 0 : 32 + h*32;

    float q[32];
    #pragma unroll
    for (int k = 0; k < 32; k += 4) {
        ushort4 u = *(const ushort4*)(qrow + qcol + k);
        q[k]=bf2f(u.x); q[k+1]=bf2f(u.y); q[k+2]=bf2f(u.z); q[k+3]=bf2f(u.w);
    }
    const float scale = 0.17677669529663687f;   // 32^-0.5
    float wmul = scale;
    if (h == 0) wmul = -scale / (1.f + __expf(-wsp[0]));

    float sc[40];
    float mx = -1e30f;
    #pragma unroll
    for (int s = 0; s < 40; ++s) {
        float dot = 0.f;
        #pragma unroll
        for (int k = 0; k < 32; k += 4) {
            const f4 kv = *(const f4*)(&Kl[h][s][k ^ hx]);
            dot += q[k]*kv[0] + q[k+1]*kv[1] + q[k+2]*kv[2] + q[k+3]*kv[3];
        }
        float v = wmul * dot;
        sc[s] = v;
        mx = fmaxf(mx, v);
    }
    float sum = 0.f;
    #pragma unroll
    for (int s = 0; s < 40; ++s) { float p = __expf(sc[s] - mx); sc[s] = p; sum += p; }
    float inv = 1.f / sum;

    float acc[32] = {};
    #pragma unroll
    for (int s = 0; s < 40; ++s) {
        float p = sc[s];
        #pragma unroll
        for (int k = 0; k < 32; k += 4) {
            const f4 vv = *(const f4*)(&Vl[h][s][k ^ hx]);
            acc[k]   += p*vv[0]; acc[k+1] += p*vv[1];
            acc[k+2] += p*vv[2]; acc[k+3] += p*vv[3];
        }
    }
    unsigned short* orow = yout + (size_t)(b*TT + t) * 128 + h*32;
    #pragma unroll
    for (int k = 0; k < 32; k += 4) {
        ushort4 u;
        u.x = f2bu(acc[k]  *inv); u.y = f2bu(acc[k+1]*inv);
        u.z = f2bu(acc[k+2]*inv); u.w = f2bu(acc[k+3]*inv);
        *(ushort4*)(orow + k) = u;
    }
}

// ---------------- head: last token y (bf16) @ traj_w + traj_b (f32 out) ----------------
__global__ __launch_bounds__(128) void head_k(
    const unsigned short* __restrict__ y,
    const float* __restrict__ tw, const float* __restrict__ tb,
    float* __restrict__ out)
{
    int b = blockIdx.x, tid = threadIdx.x;
    int tok = b*TT + (TT - 1);
    __shared__ float ys[128];
    ys[tid] = bf2f(y[(size_t)tok*128 + tid]);
    __syncthreads();
    if (tid < 120) {
        float acc = tb[tid];
        #pragma unroll 4
        for (int d = 0; d < 128; ++d) acc += ys[d] * tw[d*120 + tid];
        out[(size_t)b*120 + tid] = acc;
    }
}

extern "C" void kernel_launch(void* const* d_in, const int* in_sizes, int n_in,
                              void* d_out, int out_size, void* d_ws, size_t ws_size,
                              hipStream_t stream) {
    const float* x        = (const float*)d_in[0];
    const float* embed_w  = (const float*)d_in[1];
    const float* embed_b  = (const float*)d_in[2];
    const float* pos      = (const float*)d_in[3];
    const float* qt_w     = (const float*)d_in[4];
    const float* kt_w     = (const float*)d_in[5];
    const float* qs_w     = (const float*)d_in[6];
    const float* ks_w     = (const float*)d_in[7];
    const float* v_w      = (const float*)d_in[8];
    const float* out_w    = (const float*)d_in[9];
    const float* out_b    = (const float*)d_in[10];
    const float* w_sigma  = (const float*)d_in[11];
    const float* n1_pre_g = (const float*)d_in[12];
    const float* n1_pre_b = (const float*)d_in[13];
    const float* n1_g     = (const float*)d_in[14];
    const float* n1_b     = (const float*)d_in[15];
    const float* n2_pre_g = (const float*)d_in[16];
    const float* n2_pre_b = (const float*)d_in[17];
    const float* n2_g     = (const float*)d_in[18];
    const float* n2_b     = (const float*)d_in[19];
    const float* ff_w1    = (const float*)d_in[20];
    const float* ff_b1    = (const float*)d_in[21];
    const float* ff_w2    = (const float*)d_in[22];
    const float* ff_b2    = (const float*)d_in[23];
    const float* fn_pre_g = (const float*)d_in[24];
    const float* fn_pre_b = (const float*)d_in[25];
    const float* fn_g     = (const float*)d_in[26];
    const float* fn_b     = (const float*)d_in[27];
    const float* traj_w   = (const float*)d_in[28];
    const float* traj_b   = (const float*)d_in[29];

    // ---- workspace layout (total ~192.7 MB) ----
    char* ws = (char*)d_ws;
    float*          h       = (float*)ws;                           //  83,886,080 B
    float*          stats   = (float*)(ws + 83886080);              //   2,621,440 B
    unsigned short* y       = (unsigned short*)(ws + 86507520);     //  41,943,040 B (NTOK x 128 bf16)
    unsigned short* scratch = (unsigned short*)(ws + 128450560);    //  62,914,560 B (CHTOK x 384 bf16)
    unsigned short* wqT     = (unsigned short*)(ws + 191365120);    //     294,912 B
    unsigned short* outT    = (unsigned short*)(ws + 191660032);    //      98,304 B
    unsigned short* ff1T    = (unsigned short*)(ws + 191758336);    //     393,216 B
    unsigned short* ff2T    = (unsigned short*)(ws + 192151552);    //     393,216 B
    float*          partials= (float*)(ws + 192544768);             //     163,840 B
    float*          scal    = (float*)(ws + 192708608);             //         256 B

    pack_w_k<<<2304, 256, 0, stream>>>(qt_w, kt_w, qs_w, ks_w, v_w, out_w, ff_w1, ff_w2,
                                       wqT, outT, ff1T, ff2T);
    embed_k<<<81920, 256, 0, stream>>>(x, embed_w, embed_b, pos, h);

    for (int i = 0; i < NLAY; ++i) {
        // ---- mln1 + attention block ----
        mln_stats_k<<<40960, 256, 0, stream>>>(h, n1_pre_g + i*128, n1_pre_b + i*128, stats, partials);
        reduce_eps_k<<<1, 1024, 0, stream>>>(partials, 40960, scal);
        mln_apply_k<<<20480, 256, 0, stream>>>(h, stats, scal, n1_pre_g + i*128, n1_pre_b + i*128,
                                               n1_g + i*128, n1_b + i*128, y);
        for (int c = 0; c < 2; ++c) {
            size_t off = (size_t)c * CHTOK;
            mgemm_k<0><<<dim3(6, 640), 256, 0, stream>>>(
                y + off*128, 128, wqT + (size_t)i*49152, nullptr, scratch, 384, nullptr, 128);
            attn_k<<<2048, 256, 0, stream>>>(scratch, y + off*128, w_sigma + i);
            mgemm_k<2><<<dim3(2, 640), 256, 0, stream>>>(
                y + off*128, 128, outT + (size_t)i*16384, out_b + i*128, nullptr, 0, h + off*128, 128);
        }
        // ---- mln2 + fused FFN ----
        mln_stats_k<<<40960, 256, 0, stream>>>(h, n2_pre_g + i*128, n2_pre_b + i*128, stats, partials);
        reduce_eps_k<<<1, 1024, 0, stream>>>(partials, 40960, scal);
        mln_apply_k<<<20480, 256, 0, stream>>>(h, stats, scal, n2_pre_g + i*128, n2_pre_b + i*128,
                                               n2_g + i*128, n2_b + i*128, y);
        ffn_k<<<1280, 256, 0, stream>>>(y, ff1T + (size_t)i*65536, ff_b1 + i*512,
                                        ff2T + (size_t)i*65536, ff_b2 + i*128, h);
    }

    // ---- final mln + head ----
    mln_stats_k<<<40960, 256, 0, stream>>>(h, fn_pre_g, fn_pre_b, stats, partials);
    reduce_eps_k<<<1, 1024, 0, stream>>>(partials, 40960, scal);
    mln_apply_k<<<20480, 256, 0, stream>>>(h, stats, scal, fn_pre_g, fn_pre_b, fn_g, fn_b, y);
    head_k<<<4096, 128, 0, stream>>>(y, traj_w, traj_b, (float*)d_out);
}